// Round 4
// baseline (863.585 us; speedup 1.0000x reference)
//
#include <hip/hip_runtime.h>
#include <hip/hip_bf16.h>
#include <stdint.h>

#define BATCH 8192
#define KDIM  4096   // IN_FEATURES
#define NDIM  4096   // OUT_FEATURES

// GEMM tile config: 256x256 tile, BK=64, 8 waves (2x4), per-wave 128x64,
// 4 phases/K-tile, one-phase-ahead register pipeline, cert at end-P3.
#define BM 256
#define BN 256
#define BK 64
#define NT (KDIM / BK)   // 64

typedef __bf16 bf16x8 __attribute__((ext_vector_type(8)));
typedef float  f32x4  __attribute__((ext_vector_type(4)));

__device__ inline float bf2f(uint32_t h) {
    union { uint32_t u; float f; } c; c.u = h << 16; return c.f;
}
__device__ inline uint32_t pk2(float a, float b) {
    union { __hip_bfloat16 h[2]; uint32_t u; } o;
    o.h[0] = __float2bfloat16(a); o.h[1] = __float2bfloat16(b);
    return o.u;
}

// ---------------------------------------------------------------------------
// Kernel 0: detect dtypes device-side (graph-safe, deterministic). UNCHANGED.
// ---------------------------------------------------------------------------
__global__ void detect_kernel(const uint32_t* __restrict__ x,
                              const uint32_t* __restrict__ w,
                              const uint32_t* __restrict__ m,
                              int* __restrict__ flags) {
    __shared__ int cx, cw, all01, allf32, anybf16;
    if (threadIdx.x == 0) { cx = 0; cw = 0; all01 = 1; allf32 = 1; anybf16 = 0; }
    __syncthreads();
    int lcx = 0, lcw = 0, la01 = 1, laf = 1, lab = 0;
    #pragma unroll
    for (int jj = 0; jj < 16; ++jj) {
        int i = jj * 256 + threadIdx.x;
        uint32_t vx = x[i], vw = w[i], vm = m[i];
        uint32_t ex = (vx >> 7) & 0xFFu; if (ex >= 0x70u && ex <= 0x86u) lcx++;
        uint32_t ew = (vw >> 7) & 0xFFu; if (ew >= 0x70u && ew <= 0x86u) lcw++;
        if (vm > 1u) la01 = 0;
        if (vm != 0u && vm != 0x3F800000u) laf = 0;
        if ((vm & 0xFFFFu) == 0x3F80u || (vm >> 16) == 0x3F80u) lab = 1;
    }
    atomicAdd(&cx, lcx); atomicAdd(&cw, lcw);
    if (!la01) atomicAnd(&all01, 0);
    if (!laf)  atomicAnd(&allf32, 0);
    if (lab)   atomicOr(&anybf16, 1);
    __syncthreads();
    if (threadIdx.x == 0) {
        flags[0] = (cx < 2048) ? 1 : 0;
        flags[1] = (cw < 2048) ? 1 : 0;
        int f;
        if (all01)        f = 0;
        else if (allf32)  f = 3;
        else if (anybf16) f = 2;
        else              f = 1;
        flags[2] = f;
    }
}

// ---------------------------------------------------------------------------
// Kernel 1: x fp32 -> bf16. UNCHANGED.
// ---------------------------------------------------------------------------
__global__ void xconv_kernel(const float4* __restrict__ xf,
                             uint2* __restrict__ xb2,
                             const int* __restrict__ flags) {
    if (flags[0] == 0) return;
    const int t = blockIdx.x * 256 + threadIdx.x;
    float4 a = xf[t];
    uint2 o; o.x = pk2(a.x, a.y); o.y = pk2(a.z, a.w);
    xb2[t] = o;
}

// ---------------------------------------------------------------------------
// Kernel 2: wm = bf16(w * mask). UNCHANGED.
// ---------------------------------------------------------------------------
__global__ void wmask_kernel(const void* __restrict__ w,
                             const void* __restrict__ mask,
                             const int*  __restrict__ flags,
                             uint2* __restrict__ wm2) {
    const int fw = flags[1], fm = flags[2];
    const int t = blockIdx.x * 256 + threadIdx.x;
    float wv[4];
    if (fw) {
        float4 a = ((const float4*)w)[t];
        wv[0] = a.x; wv[1] = a.y; wv[2] = a.z; wv[3] = a.w;
    } else {
        uint2 wb = ((const uint2*)w)[t];
        wv[0] = bf2f(wb.x & 0xFFFFu); wv[1] = bf2f(wb.x >> 16);
        wv[2] = bf2f(wb.y & 0xFFFFu); wv[3] = bf2f(wb.y >> 16);
    }
    int kb[4];
    if (fm == 1) {
        uint32_t m1 = ((const uint32_t*)mask)[t];
        kb[0] = (m1 & 0xFFu) != 0u;         kb[1] = ((m1 >> 8) & 0xFFu) != 0u;
        kb[2] = ((m1 >> 16) & 0xFFu) != 0u; kb[3] = (m1 >> 24) != 0u;
    } else if (fm == 2) {
        uint2 m2 = ((const uint2*)mask)[t];
        kb[0] = (m2.x & 0xFFFFu) != 0u; kb[1] = (m2.x >> 16) != 0u;
        kb[2] = (m2.y & 0xFFFFu) != 0u; kb[3] = (m2.y >> 16) != 0u;
    } else {
        uint4 m4 = ((const uint4*)mask)[t];
        kb[0] = m4.x != 0u; kb[1] = m4.y != 0u; kb[2] = m4.z != 0u; kb[3] = m4.w != 0u;
    }
    uint2 o;
    o.x = pk2(kb[0] ? wv[0] : 0.0f, kb[1] ? wv[1] : 0.0f);
    o.y = pk2(kb[2] ? wv[2] : 0.0f, kb[3] ? wv[3] : 0.0f);
    wm2[t] = o;
}

// ---------------------------------------------------------------------------
// Kernel 3: 256x256 bf16 GEMM, C = A[M,K] * B[N,K]^T.
//   One-phase-ahead register pipeline. Phases of tile V (quadrants):
//     P1: Q00(a0,b0)   [a0,b0 read during P4(V-1)]; read b1(V);  stage B0(V+1)
//     P2: Q02(a0,b1);  read a1(V);                               stage B1(V+1)
//     P3: Q40(a1,b0);  no reads;       stage A0(V+2); vmcnt(2); BAR  <- certifies
//                                                                    tile V+1 fully
//     P4: Q42(a1,b1);  read a0(V+1),b0(V+1) from other buffer;   stage A1(V+2)
//   Every phase's ds_reads overlap the SAME phase's MFMA cluster (separate
//   pipes); the compiler's per-operand lgkmcnt gates each MFMA cluster on
//   exactly the reads it needs.
//   vmcnt accounting (steady state, 2 loads/SU): after cert at end-P3(V-1)
//   in-flight={A0(V+1)}; +A1(V+1)@P4(V-1) +B0(V+1)@P1(V) +B1(V+1)@P2(V)
//   +A0(V+2)@P3(V) = 10; vmcnt(2) drains through B1(V+1), leaving {A0(V+2)}.
//   Overwrite hazards (all >=1 barrier after lgkm-certified last read):
//     B0@P1(V) over b0(V-1) [reads done end-P1(V-1), 4 bars]
//     B1@P2(V) over b1(V-1) [done end-P2(V-1), 4 bars]
//     A0@P3(V) over a0(V)   [done end-P1(V), 2 bars]
//     A1@P4(V) over a1(V)   [lgkm'd before Q40 -> done before end-P3(V) bar]
//   Register lifetimes single-buffered (a0 rewritten P4 after last use P2,
//   a1 rewritten P2(V+1) after P4(V), b0 P4 after P3, b1 P1(V+1) after P4(V)).
//   Accumulation order over K unchanged -> numerics identical.
// ---------------------------------------------------------------------------
__global__ __launch_bounds__(512, 2)
void gemm_bt_kernel(const uint16_t* __restrict__ Araw,
                    const uint16_t* __restrict__ Aconv,
                    const uint16_t* __restrict__ B,
                    void* __restrict__ Cout,
                    const int* __restrict__ flags) {
    // buffer p at p*65536: A halves at +0,+16384; B halves at +32768,+49152
    __shared__ char smem[131072];

    const int fx = flags[0];
    const uint16_t* A = fx ? Aconv : Araw;

    const int bid = blockIdx.x;
    const int wid = (bid & 7) * 64 + (bid >> 3);   // T1: 512 % 8 == 0, bijective
    const int m0  = (wid >> 4) * BM;
    const int n0  = (wid & 15) * BN;

    const int tid  = threadIdx.x;
    const int lane = tid & 63;
    const int wave = tid >> 6;
    const int wm_  = wave >> 2;    // 0..1
    const int wn_  = wave & 3;     // 0..3

    // ---- staging precompute (pre-swizzled global sources, linear LDS dest) ----
    const int tL = tid >> 3;                                   // dest line 0..63
    const uint32_t srcSlot = (uint32_t)(((tid & 7) ^ (tL & 7)) * 16);
    const size_t K2 = (size_t)KDIM * 2;
    const char* aS[2][2]; const char* bS[2][2];                // [half][c]
    #pragma unroll
    for (int h = 0; h < 2; ++h)
        #pragma unroll
        for (int c = 0; c < 2; ++c) {
            const int r = h * 128 + tL + c * 64;
            aS[h][c] = (const char*)A + (size_t)(m0 + r) * K2 + srcSlot;
            bS[h][c] = (const char*)B + (size_t)(n0 + r) * K2 + srcSlot;
        }
    const uint32_t wdst = (uint32_t)(wave * 1024);  // HW adds lane*16

#define ISSUE_A(P, H, V) do {                                                   \
    const size_t kb_ = (size_t)(V) * 128;                                       \
    __builtin_amdgcn_global_load_lds(                                           \
        (__attribute__((address_space(1))) void*)(aS[H][0] + kb_),              \
        (__attribute__((address_space(3))) void*)(smem + (P)*65536 + (H)*16384 + wdst), 16, 0, 0); \
    __builtin_amdgcn_global_load_lds(                                           \
        (__attribute__((address_space(1))) void*)(aS[H][1] + kb_),              \
        (__attribute__((address_space(3))) void*)(smem + (P)*65536 + (H)*16384 + 8192 + wdst), 16, 0, 0); \
} while (0)

#define ISSUE_B(P, H, V) do {                                                   \
    const size_t kb_ = (size_t)(V) * 128;                                       \
    __builtin_amdgcn_global_load_lds(                                           \
        (__attribute__((address_space(1))) void*)(bS[H][0] + kb_),              \
        (__attribute__((address_space(3))) void*)(smem + (P)*65536 + 32768 + (H)*16384 + wdst), 16, 0, 0); \
    __builtin_amdgcn_global_load_lds(                                           \
        (__attribute__((address_space(1))) void*)(bS[H][1] + kb_),              \
        (__attribute__((address_space(3))) void*)(smem + (P)*65536 + 32768 + (H)*16384 + 8192 + wdst), 16, 0, 0); \
} while (0)

    // ---- fragment-read precompute ----
    const int fr = lane & 15;
    const int lq = lane >> 4;
    const uint32_t swz0 = (uint32_t)(((0 + lq) ^ (fr & 7)) * 16);
    const uint32_t swz1 = (uint32_t)(((4 + lq) ^ (fr & 7)) * 16);
    const uint32_t aRow = (uint32_t)((wm_ * 64 + fr) * 128);
    const uint32_t bRow = (uint32_t)((wn_ * 32 + fr) * 128);

    bf16x8 a0[4][2], a1[4][2], b0[2][2], b1[2][2];
    f32x4 acc[8][4] = {};

#define RD_A0(P) do {                                                           \
    _Pragma("unroll")                                                           \
    for (int mi = 0; mi < 4; ++mi) {                                            \
        a0[mi][0] = *(const bf16x8*)(smem + (P)*65536 + mi*2048 + aRow + swz0); \
        a0[mi][1] = *(const bf16x8*)(smem + (P)*65536 + mi*2048 + aRow + swz1); \
    }                                                                           \
} while (0)

#define RD_A1(P) do {                                                           \
    _Pragma("unroll")                                                           \
    for (int mi = 0; mi < 4; ++mi) {                                            \
        a1[mi][0] = *(const bf16x8*)(smem + (P)*65536 + 16384 + mi*2048 + aRow + swz0); \
        a1[mi][1] = *(const bf16x8*)(smem + (P)*65536 + 16384 + mi*2048 + aRow + swz1); \
    }                                                                           \
} while (0)

#define RD_B0(P) do {                                                           \
    _Pragma("unroll")                                                           \
    for (int ni = 0; ni < 2; ++ni) {                                            \
        b0[ni][0] = *(const bf16x8*)(smem + (P)*65536 + 32768 + ni*2048 + bRow + swz0); \
        b0[ni][1] = *(const bf16x8*)(smem + (P)*65536 + 32768 + ni*2048 + bRow + swz1); \
    }                                                                           \
} while (0)

#define RD_B1(P) do {                                                           \
    _Pragma("unroll")                                                           \
    for (int ni = 0; ni < 2; ++ni) {                                            \
        b1[ni][0] = *(const bf16x8*)(smem + (P)*65536 + 49152 + ni*2048 + bRow + swz0); \
        b1[ni][1] = *(const bf16x8*)(smem + (P)*65536 + 49152 + ni*2048 + bRow + swz1); \
    }                                                                           \
} while (0)

#define MFMA_Q(M0, N0, AF, BF) do {                                             \
    _Pragma("unroll")                                                           \
    for (int mi = 0; mi < 4; ++mi)                                              \
        _Pragma("unroll")                                                       \
        for (int ni = 0; ni < 2; ++ni) {                                        \
            acc[(M0)+mi][(N0)+ni] = __builtin_amdgcn_mfma_f32_16x16x32_bf16(    \
                AF[mi][0], BF[ni][0], acc[(M0)+mi][(N0)+ni], 0, 0, 0);          \
            acc[(M0)+mi][(N0)+ni] = __builtin_amdgcn_mfma_f32_16x16x32_bf16(    \
                AF[mi][1], BF[ni][1], acc[(M0)+mi][(N0)+ni], 0, 0, 0);          \
        }                                                                       \
} while (0)

#define BAR() do { asm volatile("" ::: "memory");                               \
    __builtin_amdgcn_s_barrier();                                               \
    asm volatile("" ::: "memory"); } while (0)

#define TILE(P, V) do {                                                         \
    /* P1: Q00 (a0,b0 already in regs); read b1(V); stage B0(V+1) */            \
    if ((V) + 1 < NT) ISSUE_B(1-(P), 0, (V)+1);                                 \
    RD_B1(P);                                                                   \
    __builtin_amdgcn_s_setprio(1);  MFMA_Q(0, 0, a0, b0);                       \
    __builtin_amdgcn_s_setprio(0);                                              \
    BAR();                                                                      \
    /* P2: Q02; read a1(V); stage B1(V+1) */                                    \
    if ((V) + 1 < NT) ISSUE_B(1-(P), 1, (V)+1);                                 \
    RD_A1(P);                                                                   \
    __builtin_amdgcn_s_setprio(1);  MFMA_Q(0, 2, a0, b1);                       \
    __builtin_amdgcn_s_setprio(0);                                              \
    BAR();                                                                      \
    /* P3: Q40; stage A0(V+2); vmcnt certifies tile V+1 */                      \
    if ((V) + 2 < NT) ISSUE_A(P, 0, (V)+2);                                     \
    __builtin_amdgcn_s_setprio(1);  MFMA_Q(4, 0, a1, b0);                       \
    __builtin_amdgcn_s_setprio(0);                                              \
    if ((V) + 2 < NT) { asm volatile("s_waitcnt vmcnt(2)" ::: "memory"); }      \
    else              { asm volatile("s_waitcnt vmcnt(0)" ::: "memory"); }      \
    BAR();                                                                      \
    /* P4: Q42; read a0(V+1),b0(V+1) from buffer 1-P; stage A1(V+2) */          \
    if ((V) + 2 < NT) ISSUE_A(P, 1, (V)+2);                                     \
    if ((V) + 1 < NT) { RD_A0(1-(P)); RD_B0(1-(P)); }                           \
    __builtin_amdgcn_s_setprio(1);  MFMA_Q(4, 2, a1, b1);                       \
    __builtin_amdgcn_s_setprio(0);                                              \
    BAR();                                                                      \
} while (0)

    // prologue: stage+certify tile 0 (buf0); put tile 1's A-units in flight
    // (the steady-state 4-outstanding at P1 entry); read P1(0) operands.
    ISSUE_A(0, 0, 0); ISSUE_A(0, 1, 0); ISSUE_B(0, 0, 0); ISSUE_B(0, 1, 0);
    asm volatile("s_waitcnt vmcnt(0)" ::: "memory");
    BAR();
    ISSUE_A(1, 0, 1);   // A0(1) @ "P3(-1)"
    ISSUE_A(1, 1, 1);   // A1(1) @ "P4(-1)"
    RD_A0(0); RD_B0(0); // operands for P1 of tile 0

    for (int it = 0; it < NT; it += 2) {
        TILE(0, it);
        TILE(1, it + 1);
    }

#undef TILE
#undef BAR
#undef MFMA_Q
#undef RD_B1
#undef RD_B0
#undef RD_A1
#undef RD_A0
#undef ISSUE_B
#undef ISSUE_A

    // Epilogue. D frag mapping: col = lane&15, row = (lane>>4)*4 + reg.
    // acc[m][n]: gm = m0 + (m>>2)*128 + wm_*64 + (m&3)*16;
    //            gn = n0 + (n>>1)*128 + wn_*32 + (n&1)*16.
    const int cn = lane & 15;
    const int rq = lane >> 4;
    if (fx) {
        float* C = (float*)Cout;
        #pragma unroll
        for (int mi = 0; mi < 8; ++mi)
            #pragma unroll
            for (int ni = 0; ni < 4; ++ni)
                #pragma unroll
                for (int r = 0; r < 4; ++r) {
                    const int gm = m0 + (mi >> 2) * 128 + wm_ * 64 + (mi & 3) * 16 + rq * 4 + r;
                    const int gn = n0 + (ni >> 1) * 128 + wn_ * 32 + (ni & 1) * 16 + cn;
                    C[(size_t)gm * NDIM + gn] = acc[mi][ni][r];
                }
    } else {
        __hip_bfloat16* C = (__hip_bfloat16*)Cout;
        #pragma unroll
        for (int mi = 0; mi < 8; ++mi)
            #pragma unroll
            for (int ni = 0; ni < 4; ++ni)
                #pragma unroll
                for (int r = 0; r < 4; ++r) {
                    const int gm = m0 + (mi >> 2) * 128 + wm_ * 64 + (mi & 3) * 16 + rq * 4 + r;
                    const int gn = n0 + (ni >> 1) * 128 + wn_ * 32 + (ni & 1) * 16 + cn;
                    C[(size_t)gm * NDIM + gn] = __float2bfloat16(acc[mi][ni][r]);
                }
    }
}

extern "C" void kernel_launch(void* const* d_in, const int* in_sizes, int n_in,
                              void* d_out, int out_size, void* d_ws, size_t ws_size,
                              hipStream_t stream) {
    const void* x    = d_in[0];
    const void* w    = d_in[1];
    const void* mask = d_in[2];

    int*      flags = (int*)d_ws;
    uint16_t* wm    = (uint16_t*)((char*)d_ws + 256);
    uint16_t* xb    = (uint16_t*)((char*)d_ws + 256 + (size_t)NDIM * KDIM * 2);

    detect_kernel<<<1, 256, 0, stream>>>((const uint32_t*)x, (const uint32_t*)w,
                                         (const uint32_t*)mask, flags);

    xconv_kernel<<<(BATCH * KDIM / 4) / 256, 256, 0, stream>>>(
        (const float4*)x, (uint2*)xb, flags);

    wmask_kernel<<<(NDIM * KDIM / 4) / 256, 256, 0, stream>>>(
        w, mask, flags, (uint2*)wm);

    gemm_bt_kernel<<<dim3((BATCH / BM) * (NDIM / BN)), 512, 0, stream>>>(
        (const uint16_t*)x, xb, wm, d_out, flags);
}

// Round 5
// 564.662 us; speedup vs baseline: 1.5294x; 1.5294x over previous
//
#include <hip/hip_runtime.h>
#include <hip/hip_bf16.h>
#include <stdint.h>

#define BATCH 8192
#define KDIM  4096   // IN_FEATURES
#define NDIM  4096   // OUT_FEATURES

// GEMM tile config: 256x256 tile, BK=32, 8 waves (2x4), per-wave 128x64.
// Double-buffered 64 KiB LDS -> 2 blocks/CU (16 waves/CU) for TLP overlap.
// One phase + ONE barrier per K-tile.
#define BM 256
#define BN 256
#define BK 32
#define NT (KDIM / BK)   // 128

typedef __bf16 bf16x8 __attribute__((ext_vector_type(8)));
typedef float  f32x4  __attribute__((ext_vector_type(4)));

__device__ inline float bf2f(uint32_t h) {
    union { uint32_t u; float f; } c; c.u = h << 16; return c.f;
}
__device__ inline uint32_t pk2(float a, float b) {
    union { __hip_bfloat16 h[2]; uint32_t u; } o;
    o.h[0] = __float2bfloat16(a); o.h[1] = __float2bfloat16(b);
    return o.u;
}

// ---------------------------------------------------------------------------
// Kernel 0: detect dtypes device-side (graph-safe, deterministic). UNCHANGED.
// ---------------------------------------------------------------------------
__global__ void detect_kernel(const uint32_t* __restrict__ x,
                              const uint32_t* __restrict__ w,
                              const uint32_t* __restrict__ m,
                              int* __restrict__ flags) {
    __shared__ int cx, cw, all01, allf32, anybf16;
    if (threadIdx.x == 0) { cx = 0; cw = 0; all01 = 1; allf32 = 1; anybf16 = 0; }
    __syncthreads();
    int lcx = 0, lcw = 0, la01 = 1, laf = 1, lab = 0;
    #pragma unroll
    for (int jj = 0; jj < 16; ++jj) {
        int i = jj * 256 + threadIdx.x;
        uint32_t vx = x[i], vw = w[i], vm = m[i];
        uint32_t ex = (vx >> 7) & 0xFFu; if (ex >= 0x70u && ex <= 0x86u) lcx++;
        uint32_t ew = (vw >> 7) & 0xFFu; if (ew >= 0x70u && ew <= 0x86u) lcw++;
        if (vm > 1u) la01 = 0;
        if (vm != 0u && vm != 0x3F800000u) laf = 0;
        if ((vm & 0xFFFFu) == 0x3F80u || (vm >> 16) == 0x3F80u) lab = 1;
    }
    atomicAdd(&cx, lcx); atomicAdd(&cw, lcw);
    if (!la01) atomicAnd(&all01, 0);
    if (!laf)  atomicAnd(&allf32, 0);
    if (lab)   atomicOr(&anybf16, 1);
    __syncthreads();
    if (threadIdx.x == 0) {
        flags[0] = (cx < 2048) ? 1 : 0;
        flags[1] = (cw < 2048) ? 1 : 0;
        int f;
        if (all01)        f = 0;
        else if (allf32)  f = 3;
        else if (anybf16) f = 2;
        else              f = 1;
        flags[2] = f;
    }
}

// ---------------------------------------------------------------------------
// Kernel 1: x fp32 -> bf16. UNCHANGED.
// ---------------------------------------------------------------------------
__global__ void xconv_kernel(const float4* __restrict__ xf,
                             uint2* __restrict__ xb2,
                             const int* __restrict__ flags) {
    if (flags[0] == 0) return;
    const int t = blockIdx.x * 256 + threadIdx.x;
    float4 a = xf[t];
    uint2 o; o.x = pk2(a.x, a.y); o.y = pk2(a.z, a.w);
    xb2[t] = o;
}

// ---------------------------------------------------------------------------
// Kernel 2: wm = bf16(w * mask). UNCHANGED.
// ---------------------------------------------------------------------------
__global__ void wmask_kernel(const void* __restrict__ w,
                             const void* __restrict__ mask,
                             const int*  __restrict__ flags,
                             uint2* __restrict__ wm2) {
    const int fw = flags[1], fm = flags[2];
    const int t = blockIdx.x * 256 + threadIdx.x;
    float wv[4];
    if (fw) {
        float4 a = ((const float4*)w)[t];
        wv[0] = a.x; wv[1] = a.y; wv[2] = a.z; wv[3] = a.w;
    } else {
        uint2 wb = ((const uint2*)w)[t];
        wv[0] = bf2f(wb.x & 0xFFFFu); wv[1] = bf2f(wb.x >> 16);
        wv[2] = bf2f(wb.y & 0xFFFFu); wv[3] = bf2f(wb.y >> 16);
    }
    int kb[4];
    if (fm == 1) {
        uint32_t m1 = ((const uint32_t*)mask)[t];
        kb[0] = (m1 & 0xFFu) != 0u;         kb[1] = ((m1 >> 8) & 0xFFu) != 0u;
        kb[2] = ((m1 >> 16) & 0xFFu) != 0u; kb[3] = (m1 >> 24) != 0u;
    } else if (fm == 2) {
        uint2 m2 = ((const uint2*)mask)[t];
        kb[0] = (m2.x & 0xFFFFu) != 0u; kb[1] = (m2.x >> 16) != 0u;
        kb[2] = (m2.y & 0xFFFFu) != 0u; kb[3] = (m2.y >> 16) != 0u;
    } else {
        uint4 m4 = ((const uint4*)mask)[t];
        kb[0] = m4.x != 0u; kb[1] = m4.y != 0u; kb[2] = m4.z != 0u; kb[3] = m4.w != 0u;
    }
    uint2 o;
    o.x = pk2(kb[0] ? wv[0] : 0.0f, kb[1] ? wv[1] : 0.0f);
    o.y = pk2(kb[2] ? wv[2] : 0.0f, kb[3] ? wv[3] : 0.0f);
    wm2[t] = o;
}

// ---------------------------------------------------------------------------
// Kernel 3: 256x256 bf16 GEMM, C = A[M,K] * B[N,K]^T — BK=32, double-buffered
// 64 KiB LDS (2 blocks/CU), one barrier per K-tile.
//   Per K-tile V (buf P = V&1):
//     { ISSUE stage(V+1) -> buf 1-P (4 global_load_lds: A0,A1,B0,B1);
//       12 ds_read_b128 from buf P; 32 MFMA (compiler-interleaved lgkm);
//       s_waitcnt vmcnt(0); s_barrier }
//   Safety with one barrier: every ds_read's consumer MFMA precedes the
//   barrier, so lgkm waits guarantee reads complete before each wave's
//   barrier arrival; stage(V+1) after the barrier overwrites buf 1-P whose
//   last readers certified at the previous barrier. vmcnt(0) drains only
//   the 4 loads issued at this tile's start (latency hidden under the 32
//   MFMA + covered by the co-resident second block).
//   LDS layout: 64-B rows (32 bf16); phys 16B-slot = logical ^ ((row>>1)&3)
//   (bijective involution; 2-way-free per 16-lane b128 phase group).
//   Applied on pre-swizzled global SOURCE (linear gl_lds dest) and on the
//   ds_read address — same involution both sides.
//   Accumulation order over K unchanged (ascending 32-chunks) -> numerics
//   identical to all previous passing versions.
//   Register discipline (R4 lesson): nothing live across barriers except
//   acc; operands a[8]+b[4] = 48 VGPR within-tile only.
// ---------------------------------------------------------------------------
__global__ __launch_bounds__(512, 2)
void gemm_bt_kernel(const uint16_t* __restrict__ Araw,
                    const uint16_t* __restrict__ Aconv,
                    const uint16_t* __restrict__ B,
                    void* __restrict__ Cout,
                    const int* __restrict__ flags) {
    // buffer P at P*32768: A [256 rows][64 B] at +0 (16 KiB),
    //                      B [256 rows][64 B] at +16384 (16 KiB)
    __shared__ char smem[65536];

    const int fx = flags[0];
    const uint16_t* A = fx ? Aconv : Araw;

    const int bid = blockIdx.x;
    const int wid = (bid & 7) * 64 + (bid >> 3);   // T1: 512 % 8 == 0, bijective
    const int m0  = (wid >> 4) * BM;
    const int n0  = (wid & 15) * BN;

    const int tid  = threadIdx.x;
    const int lane = tid & 63;
    const int wave = tid >> 6;
    const int wm_  = wave >> 2;    // 0..1 (row panel, 128 rows)
    const int wn_  = wave & 3;     // 0..3 (col panel, 64 cols)

    // ---- staging precompute ----
    // Unit = 8 KiB = 128 rows x 64 B; thread t covers row c*128 + (t>>2),
    // phys slot t&3. Pre-swizzled global source slot = (t&3) ^ ((t>>3)&3).
    const int tRow  = tid >> 2;                       // 0..127
    const uint32_t tSlot = (uint32_t)(((tid & 3) ^ ((tid >> 3) & 3)) * 16);
    const size_t K2 = (size_t)KDIM * 2;
    const char* aSrc[2]; const char* bSrc[2];
    #pragma unroll
    for (int c = 0; c < 2; ++c) {
        aSrc[c] = (const char*)A + (size_t)(m0 + c * 128 + tRow) * K2 + tSlot;
        bSrc[c] = (const char*)B + (size_t)(n0 + c * 128 + tRow) * K2 + tSlot;
    }
    const uint32_t wdst = (uint32_t)(wave * 1024);    // HW adds lane*16

#define ISSUE(P, V) do {                                                        \
    const size_t kb_ = (size_t)(V) * 64;  /* BK=32 bf16 = 64 B per row */       \
    __builtin_amdgcn_global_load_lds(                                           \
        (__attribute__((address_space(1))) void*)(aSrc[0] + kb_),               \
        (__attribute__((address_space(3))) void*)(smem + (P)*32768 + wdst), 16, 0, 0); \
    __builtin_amdgcn_global_load_lds(                                           \
        (__attribute__((address_space(1))) void*)(aSrc[1] + kb_),               \
        (__attribute__((address_space(3))) void*)(smem + (P)*32768 + 8192 + wdst), 16, 0, 0); \
    __builtin_amdgcn_global_load_lds(                                           \
        (__attribute__((address_space(1))) void*)(bSrc[0] + kb_),               \
        (__attribute__((address_space(3))) void*)(smem + (P)*32768 + 16384 + wdst), 16, 0, 0); \
    __builtin_amdgcn_global_load_lds(                                           \
        (__attribute__((address_space(1))) void*)(bSrc[1] + kb_),               \
        (__attribute__((address_space(3))) void*)(smem + (P)*32768 + 24576 + wdst), 16, 0, 0); \
} while (0)

    // ---- fragment-read precompute ----
    // Lane reads logical k-slot lq of row R; phys slot = lq ^ ((R>>1)&3).
    // R = wm_*128 + mi*16 + fr (A) or wn_*64 + ni*16 + fr (B): the panel and
    // mi/ni terms are multiples of 8 rows, so (R>>1)&3 == (fr>>1)&3.
    const int fr = lane & 15;
    const int lq = lane >> 4;      // 0..3
    const uint32_t swz = (uint32_t)((lq ^ ((fr >> 1) & 3)) * 16);
    const uint32_t aRd = (uint32_t)((wm_ * 128 + fr) * 64) + swz;
    const uint32_t bRd = 16384u + (uint32_t)((wn_ * 64 + fr) * 64) + swz;

    bf16x8 a[8], b[4];
    f32x4 acc[8][4] = {};

#define RD(P) do {                                                              \
    _Pragma("unroll")                                                           \
    for (int mi = 0; mi < 8; ++mi)                                              \
        a[mi] = *(const bf16x8*)(smem + (P)*32768 + mi*1024 + aRd);             \
    _Pragma("unroll")                                                           \
    for (int ni = 0; ni < 4; ++ni)                                              \
        b[ni] = *(const bf16x8*)(smem + (P)*32768 + ni*1024 + bRd);             \
} while (0)

#define MFMA_ALL() do {                                                         \
    _Pragma("unroll")                                                           \
    for (int mi = 0; mi < 8; ++mi)                                              \
        _Pragma("unroll")                                                       \
        for (int ni = 0; ni < 4; ++ni)                                          \
            acc[mi][ni] = __builtin_amdgcn_mfma_f32_16x16x32_bf16(              \
                a[mi], b[ni], acc[mi][ni], 0, 0, 0);                            \
} while (0)

#define BAR() do { asm volatile("" ::: "memory");                               \
    __builtin_amdgcn_s_barrier();                                               \
    asm volatile("" ::: "memory"); } while (0)

#define TILE(P, V) do {                                                         \
    if ((V) + 1 < NT) ISSUE(1-(P), (V)+1);                                      \
    RD(P);                                                                      \
    __builtin_amdgcn_s_setprio(1);  MFMA_ALL();  __builtin_amdgcn_s_setprio(0); \
    asm volatile("s_waitcnt vmcnt(0)" ::: "memory");                            \
    BAR();                                                                      \
} while (0)

    // prologue: stage tile 0 into buf 0 and certify it
    ISSUE(0, 0);
    asm volatile("s_waitcnt vmcnt(0)" ::: "memory");
    BAR();

    for (int it = 0; it < NT; it += 2) {
        TILE(0, it);
        TILE(1, it + 1);
    }

#undef TILE
#undef BAR
#undef MFMA_ALL
#undef RD
#undef ISSUE

    // Epilogue. D frag mapping: col = lane&15, row = (lane>>4)*4 + reg.
    // acc[mi][ni]: gm = m0 + wm_*128 + mi*16 + (lane>>4)*4 + r;
    //              gn = n0 + wn_*64 + ni*16 + (lane&15).
    const int cn = lane & 15;
    const int rq = lane >> 4;
    if (fx) {
        float* C = (float*)Cout;
        #pragma unroll
        for (int mi = 0; mi < 8; ++mi)
            #pragma unroll
            for (int ni = 0; ni < 4; ++ni)
                #pragma unroll
                for (int r = 0; r < 4; ++r) {
                    const int gm = m0 + wm_ * 128 + mi * 16 + rq * 4 + r;
                    const int gn = n0 + wn_ * 64 + ni * 16 + cn;
                    C[(size_t)gm * NDIM + gn] = acc[mi][ni][r];
                }
    } else {
        __hip_bfloat16* C = (__hip_bfloat16*)Cout;
        #pragma unroll
        for (int mi = 0; mi < 8; ++mi)
            #pragma unroll
            for (int ni = 0; ni < 4; ++ni)
                #pragma unroll
                for (int r = 0; r < 4; ++r) {
                    const int gm = m0 + wm_ * 128 + mi * 16 + rq * 4 + r;
                    const int gn = n0 + wn_ * 64 + ni * 16 + cn;
                    C[(size_t)gm * NDIM + gn] = __float2bfloat16(acc[mi][ni][r]);
                }
    }
}

extern "C" void kernel_launch(void* const* d_in, const int* in_sizes, int n_in,
                              void* d_out, int out_size, void* d_ws, size_t ws_size,
                              hipStream_t stream) {
    const void* x    = d_in[0];
    const void* w    = d_in[1];
    const void* mask = d_in[2];

    int*      flags = (int*)d_ws;
    uint16_t* wm    = (uint16_t*)((char*)d_ws + 256);
    uint16_t* xb    = (uint16_t*)((char*)d_ws + 256 + (size_t)NDIM * KDIM * 2);

    detect_kernel<<<1, 256, 0, stream>>>((const uint32_t*)x, (const uint32_t*)w,
                                         (const uint32_t*)mask, flags);

    xconv_kernel<<<(BATCH * KDIM / 4) / 256, 256, 0, stream>>>(
        (const float4*)x, (uint2*)xb, flags);

    wmask_kernel<<<(NDIM * KDIM / 4) / 256, 256, 0, stream>>>(
        w, mask, flags, (uint2*)wm);

    gemm_bt_kernel<<<dim3((BATCH / BM) * (NDIM / BN)), 512, 0, stream>>>(
        (const uint16_t*)x, xb, wm, d_out, flags);
}